// Round 1
// baseline (891.698 us; speedup 1.0000x reference)
//
#include <hip/hip_runtime.h>

// GCN 3-layer: N=100000 nodes, E=1600000 edges, dims 20->64->48->32.
// Strategy: build CSR-by-dst once (counting sort, int atomics only), then per
// layer: skinny GEMM (BN-affine+ReLU of previous layer fused into load) ->
// per-node wave gather aggregation -> BN stats. Final BN applied to d_out.
// Workspace use: ~66 MB.

#define NN 100000
#define NE 1600000
constexpr float BN_EPS_F = 1e-5f;

// ---------------- CSR build ----------------

__global__ void count_deg(const int* __restrict__ dst, int* __restrict__ deg, int e) {
  int i = blockIdx.x * blockDim.x + threadIdx.x;
  if (i < e) atomicAdd(&deg[dst[i]], 1);
}

// chunk=1024 per block, block=256 threads (4 elems/thread)
__global__ void scan_block_sums(const int* __restrict__ deg, int* __restrict__ bsums, int n) {
  __shared__ int sd[256];
  int tid = threadIdx.x;
  int base = blockIdx.x * 1024;
  int s = 0;
#pragma unroll
  for (int j = 0; j < 4; j++) {
    int idx = base + tid * 4 + j;
    if (idx < n) s += deg[idx];
  }
  sd[tid] = s;
  __syncthreads();
  for (int o = 128; o > 0; o >>= 1) {
    if (tid < o) sd[tid] += sd[tid + o];
    __syncthreads();
  }
  if (tid == 0) bsums[blockIdx.x] = sd[0];
}

// single block: exclusive-scan bsums[nb] (nb<=128), write rowptr[n]=total
__global__ void scan_bsums(int* __restrict__ bsums, int nb, int* __restrict__ rowptr, int n) {
  __shared__ int sd[128];
  int tid = threadIdx.x;
  int v = (tid < nb) ? bsums[tid] : 0;
  sd[tid] = v;
  __syncthreads();
  for (int o = 1; o < 128; o <<= 1) {
    int t = (tid >= o) ? sd[tid - o] : 0;
    __syncthreads();
    sd[tid] += t;
    __syncthreads();
  }
  if (tid < nb) bsums[tid] = sd[tid] - v;  // exclusive
  if (tid == nb - 1) rowptr[n] = sd[tid];  // grand total
}

__global__ void scan_write_rowptr(const int* __restrict__ deg, const int* __restrict__ bsums,
                                  int* __restrict__ rowptr, int* __restrict__ cursor, int n) {
  __shared__ int sd[256];
  int tid = threadIdx.x;
  int base = blockIdx.x * 1024;
  int c[4];
  int s = 0;
#pragma unroll
  for (int j = 0; j < 4; j++) {
    int idx = base + tid * 4 + j;
    c[j] = (idx < n) ? deg[idx] : 0;
    s += c[j];
  }
  sd[tid] = s;
  __syncthreads();
  for (int o = 1; o < 256; o <<= 1) {
    int t = (tid >= o) ? sd[tid - o] : 0;
    __syncthreads();
    sd[tid] += t;
    __syncthreads();
  }
  int off = bsums[blockIdx.x] + sd[tid] - s;  // exclusive prefix of this thread's run
#pragma unroll
  for (int j = 0; j < 4; j++) {
    int idx = base + tid * 4 + j;
    if (idx < n) {
      rowptr[idx] = off;
      cursor[idx] = off;
      off += c[j];
    }
  }
}

__global__ void compute_dinv(const int* __restrict__ deg, float* __restrict__ dinv, int n) {
  int i = blockIdx.x * blockDim.x + threadIdx.x;
  if (i < n) dinv[i] = rsqrtf((float)(deg[i] + 1));  // +1 self loop
}

__global__ void fill_csr(const int* __restrict__ src, const int* __restrict__ dst,
                         const float* __restrict__ dinv, int* __restrict__ cursor,
                         int* __restrict__ csr_src, float* __restrict__ csr_norm, int e) {
  int i = blockIdx.x * blockDim.x + threadIdx.x;
  if (i < e) {
    int s = src[i], d = dst[i];
    int p = atomicAdd(&cursor[d], 1);
    csr_src[p] = s;
    csr_norm[p] = dinv[s] * dinv[d];
  }
}

// ---------------- dense skinny GEMM with fused BN-affine+ReLU on input ----------------
// h: [n,K] row-major, W: [K,C] row-major, out: [n,C]. scale/shift nullable.

template <int K, int C, int R>
__global__ void gemm_affine(const float* __restrict__ h, const float* __restrict__ W,
                            const float* __restrict__ scale, const float* __restrict__ shift,
                            float* __restrict__ out, int n) {
  __shared__ float Wl[K * C];
  __shared__ float Hl[R][K];
  int tid = threadIdx.x;
  for (int i = tid; i < K * C; i += 256) Wl[i] = W[i];
  int row0 = blockIdx.x * R;
  for (int i = tid; i < R * K; i += 256) {
    int r = i / K, k = i % K;
    int row = row0 + r;
    float v = 0.f;
    if (row < n) v = h[row * K + k];
    if (scale) {
      v = v * scale[k] + shift[k];
      v = fmaxf(v, 0.f);
    }
    Hl[r][k] = v;
  }
  __syncthreads();
  int r = tid / C, c = tid % C;
  if (r < R) {
    int row = row0 + r;
    if (row < n) {
      float acc = 0.f;
#pragma unroll
      for (int k = 0; k < K; k++) acc = fmaf(Hl[r][k], Wl[k * C + c], acc);
      out[row * C + c] = acc;
    }
  }
}

// ---------------- aggregation: one wave per node, lane = feature ----------------

template <int C>
__global__ void aggregate(const float* __restrict__ m, const int* __restrict__ rowptr,
                          const int* __restrict__ csr_src, const float* __restrict__ csr_norm,
                          const float* __restrict__ dinv, const float* __restrict__ bias,
                          float* __restrict__ out, int n) {
  int wave = threadIdx.x >> 6;
  int lane = threadIdx.x & 63;
  int d = blockIdx.x * 4 + wave;
  if (d >= n) return;
  int start = rowptr[d], end = rowptr[d + 1];
  float dd = dinv[d];
  float acc = 0.f;
  if (lane < C) acc = dd * dd * m[d * C + lane];  // self loop
  for (int j = start; j < end; j++) {
    int s = csr_src[j];
    float nm = csr_norm[j];
    if (lane < C) acc += nm * m[s * C + lane];
  }
  if (lane < C) out[d * C + lane] = acc + bias[lane];
}

// ---------------- BN stats / finalize / apply ----------------

template <int C>
__global__ void bn_stats(const float* __restrict__ h, float* __restrict__ gsum,
                         float* __restrict__ gsq, int n) {
  __shared__ float ssum[256], ssq[256];
  const int Y = 256 / C;
  int tid = threadIdx.x;
  int c = tid % C, y = tid / C;
  float s = 0.f, q = 0.f;
  if (tid < C * Y) {
    for (int r = blockIdx.x * Y + y; r < n; r += gridDim.x * Y) {
      float v = h[r * C + c];
      s += v;
      q += v * v;
    }
  }
  ssum[tid] = s;
  ssq[tid] = q;
  __syncthreads();
  if (tid < C) {  // tid<C implies y==0
    for (int yy = 1; yy < Y; yy++) {
      s += ssum[tid + yy * C];
      q += ssq[tid + yy * C];
    }
    atomicAdd(&gsum[tid], s);
    atomicAdd(&gsq[tid], q);
  }
}

__global__ void bn_finalize(const float* __restrict__ gsum, const float* __restrict__ gsq,
                            const float* __restrict__ g, const float* __restrict__ beta,
                            float* __restrict__ scale, float* __restrict__ shift, int C,
                            float invn) {
  int i = threadIdx.x;
  if (i < C) {
    float mean = gsum[i] * invn;
    float var = gsq[i] * invn - mean * mean;
    var = fmaxf(var, 0.f);
    float inv = rsqrtf(var + BN_EPS_F);
    float sc = g[i] * inv;
    scale[i] = sc;
    shift[i] = beta[i] - mean * sc;
  }
}

__global__ void bn_apply_out(const float* __restrict__ h, const float* __restrict__ scale,
                             const float* __restrict__ shift, float* __restrict__ out, int total) {
  int i = blockIdx.x * blockDim.x + threadIdx.x;
  if (i < total) {
    int c = i & 31;
    out[i] = h[i] * scale[c] + shift[c];
  }
}

// ---------------- launch ----------------

extern "C" void kernel_launch(void* const* d_in, const int* in_sizes, int n_in,
                              void* d_out, int out_size, void* d_ws, size_t ws_size,
                              hipStream_t stream) {
  const float* x = (const float*)d_in[0];
  const int* ei = (const int*)d_in[1];
  const float* W1 = (const float*)d_in[2];
  const float* b1 = (const float*)d_in[3];
  const float* g1 = (const float*)d_in[4];
  const float* be1 = (const float*)d_in[5];
  const float* W2 = (const float*)d_in[6];
  const float* b2 = (const float*)d_in[7];
  const float* g2 = (const float*)d_in[8];
  const float* be2 = (const float*)d_in[9];
  const float* W3 = (const float*)d_in[10];
  const float* b3 = (const float*)d_in[11];
  const float* g3 = (const float*)d_in[12];
  const float* be3 = (const float*)d_in[13];
  float* out = (float*)d_out;

  const int* src = ei;       // edge_index row 0
  const int* dst = ei + NE;  // edge_index row 1

  char* ws = (char*)d_ws;
  size_t off = 0;
  auto alloc = [&](size_t bytes) -> void* {
    void* p = ws + off;
    off += bytes;
    off = (off + 255) & ~(size_t)255;
    return p;
  };
  int* deg = (int*)alloc(NN * 4);
  int* rowptr = (int*)alloc((NN + 1) * 4);
  int* cursor = (int*)alloc(NN * 4);
  int* bsums = (int*)alloc(128 * 4);
  int* csr_src = (int*)alloc(NE * 4);
  float* csr_norm = (float*)alloc(NE * 4);
  float* dinv = (float*)alloc(NN * 4);
  float* gsum = (float*)alloc(3 * 128 * 4);        // per layer: [sum64 | sq64]
  float* scsh = (float*)alloc(3 * 128 * 4);        // per layer: [scale64 | shift64]
  float* bufA = (float*)alloc((size_t)NN * 64 * 4);
  float* bufB = (float*)alloc((size_t)NN * 64 * 4);

  hipMemsetAsync(deg, 0, NN * 4, stream);
  hipMemsetAsync(gsum, 0, 3 * 128 * 4, stream);

  const int nb = (NN + 1023) / 1024;  // 98
  count_deg<<<(NE + 255) / 256, 256, 0, stream>>>(dst, deg, NE);
  scan_block_sums<<<nb, 256, 0, stream>>>(deg, bsums, NN);
  scan_bsums<<<1, 128, 0, stream>>>(bsums, nb, rowptr, NN);
  scan_write_rowptr<<<nb, 256, 0, stream>>>(deg, bsums, rowptr, cursor, NN);
  compute_dinv<<<(NN + 255) / 256, 256, 0, stream>>>(deg, dinv, NN);
  fill_csr<<<(NE + 255) / 256, 256, 0, stream>>>(src, dst, dinv, cursor, csr_src, csr_norm, NE);

  const float invn = 1.f / (float)NN;

  // layer 1: x[.,20] @ W1 -> 64
  gemm_affine<20, 64, 4><<<(NN + 3) / 4, 256, 0, stream>>>(x, W1, nullptr, nullptr, bufA, NN);
  aggregate<64><<<(NN + 3) / 4, 256, 0, stream>>>(bufA, rowptr, csr_src, csr_norm, dinv, b1, bufB, NN);
  bn_stats<64><<<256, 256, 0, stream>>>(bufB, gsum + 0, gsum + 64, NN);
  bn_finalize<<<1, 64, 0, stream>>>(gsum + 0, gsum + 64, g1, be1, scsh + 0, scsh + 64, 64, invn);

  // layer 2: relu(bn(h)) @ W2 -> 48
  gemm_affine<64, 48, 5><<<(NN + 4) / 5, 256, 0, stream>>>(bufB, W2, scsh + 0, scsh + 64, bufA, NN);
  aggregate<48><<<(NN + 3) / 4, 256, 0, stream>>>(bufA, rowptr, csr_src, csr_norm, dinv, b2, bufB, NN);
  bn_stats<48><<<256, 256, 0, stream>>>(bufB, gsum + 128, gsum + 192, NN);
  bn_finalize<<<1, 64, 0, stream>>>(gsum + 128, gsum + 192, g2, be2, scsh + 128, scsh + 192, 48, invn);

  // layer 3: relu(bn(h)) @ W3 -> 32
  gemm_affine<48, 32, 8><<<(NN + 7) / 8, 256, 0, stream>>>(bufB, W3, scsh + 128, scsh + 192, bufA, NN);
  aggregate<32><<<(NN + 3) / 4, 256, 0, stream>>>(bufA, rowptr, csr_src, csr_norm, dinv, b3, bufB, NN);
  bn_stats<32><<<256, 256, 0, stream>>>(bufB, gsum + 256, gsum + 320, NN);
  bn_finalize<<<1, 64, 0, stream>>>(gsum + 256, gsum + 320, g3, be3, scsh + 256, scsh + 320, 32, invn);

  bn_apply_out<<<(NN * 32 + 255) / 256, 256, 0, stream>>>(bufB, scsh + 256, scsh + 320, out, NN * 32);
}

// Round 2
// 642.390 us; speedup vs baseline: 1.3881x; 1.3881x over previous
//
#include <hip/hip_runtime.h>

// GCN 3-layer: N=100000 nodes, E=1600000 edges, dims 20->64->48->32.
// CSR-by-dst build (counting sort), per layer: skinny GEMM (fused BN+ReLU of
// previous layer) -> per-node wave gather aggregation (ILP-unrolled edge loop)
// -> BN stats. Final BN applied into d_out.

#define NN 100000
#define NE 1600000
constexpr float BN_EPS_F = 1e-5f;

// ---------------- CSR build ----------------

__global__ void count_deg(const int* __restrict__ dst, int* __restrict__ deg, int e) {
  int i = blockIdx.x * blockDim.x + threadIdx.x;
  if (i < e) atomicAdd(&deg[dst[i]], 1);
}

__global__ void scan_block_sums(const int* __restrict__ deg, int* __restrict__ bsums, int n) {
  __shared__ int sd[256];
  int tid = threadIdx.x;
  int base = blockIdx.x * 1024;
  int s = 0;
#pragma unroll
  for (int j = 0; j < 4; j++) {
    int idx = base + tid * 4 + j;
    if (idx < n) s += deg[idx];
  }
  sd[tid] = s;
  __syncthreads();
  for (int o = 128; o > 0; o >>= 1) {
    if (tid < o) sd[tid] += sd[tid + o];
    __syncthreads();
  }
  if (tid == 0) bsums[blockIdx.x] = sd[0];
}

__global__ void scan_bsums(int* __restrict__ bsums, int nb, int* __restrict__ rowptr, int n) {
  __shared__ int sd[128];
  int tid = threadIdx.x;
  int v = (tid < nb) ? bsums[tid] : 0;
  sd[tid] = v;
  __syncthreads();
  for (int o = 1; o < 128; o <<= 1) {
    int t = (tid >= o) ? sd[tid - o] : 0;
    __syncthreads();
    sd[tid] += t;
    __syncthreads();
  }
  if (tid < nb) bsums[tid] = sd[tid] - v;  // exclusive
  if (tid == nb - 1) rowptr[n] = sd[tid];  // grand total
}

__global__ void scan_write_rowptr(const int* __restrict__ deg, const int* __restrict__ bsums,
                                  int* __restrict__ rowptr, int* __restrict__ cursor, int n) {
  __shared__ int sd[256];
  int tid = threadIdx.x;
  int base = blockIdx.x * 1024;
  int c[4];
  int s = 0;
#pragma unroll
  for (int j = 0; j < 4; j++) {
    int idx = base + tid * 4 + j;
    c[j] = (idx < n) ? deg[idx] : 0;
    s += c[j];
  }
  sd[tid] = s;
  __syncthreads();
  for (int o = 1; o < 256; o <<= 1) {
    int t = (tid >= o) ? sd[tid - o] : 0;
    __syncthreads();
    sd[tid] += t;
    __syncthreads();
  }
  int off = bsums[blockIdx.x] + sd[tid] - s;
#pragma unroll
  for (int j = 0; j < 4; j++) {
    int idx = base + tid * 4 + j;
    if (idx < n) {
      rowptr[idx] = off;
      cursor[idx] = off;
      off += c[j];
    }
  }
}

__global__ void compute_dinv(const int* __restrict__ deg, float* __restrict__ dinv, int n) {
  int i = blockIdx.x * blockDim.x + threadIdx.x;
  if (i < n) dinv[i] = rsqrtf((float)(deg[i] + 1));  // +1 self loop
}

__global__ void fill_csr(const int* __restrict__ src, const int* __restrict__ dst,
                         const float* __restrict__ dinv, int* __restrict__ cursor,
                         int* __restrict__ csr_src, float* __restrict__ csr_norm, int e) {
  int i = blockIdx.x * blockDim.x + threadIdx.x;
  if (i < e) {
    int s = src[i], d = dst[i];
    int p = atomicAdd(&cursor[d], 1);
    csr_src[p] = s;
    csr_norm[p] = dinv[s] * dinv[d];
  }
}

// ---------------- dense skinny GEMM with fused BN-affine+ReLU on input ----------------

template <int K, int C, int R>
__global__ void gemm_affine(const float* __restrict__ h, const float* __restrict__ W,
                            const float* __restrict__ scale, const float* __restrict__ shift,
                            float* __restrict__ out, int n) {
  __shared__ float Wl[K * C];
  __shared__ float Hl[R][K];
  int tid = threadIdx.x;
  for (int i = tid; i < K * C; i += 256) Wl[i] = W[i];
  int row0 = blockIdx.x * R;
  for (int i = tid; i < R * K; i += 256) {
    int r = i / K, k = i % K;
    int row = row0 + r;
    float v = 0.f;
    if (row < n) v = h[row * K + k];
    if (scale) {
      v = v * scale[k] + shift[k];
      v = fmaxf(v, 0.f);
    }
    Hl[r][k] = v;
  }
  __syncthreads();
  int r = tid / C, c = tid % C;
  if (r < R) {
    int row = row0 + r;
    if (row < n) {
      float acc = 0.f;
#pragma unroll
      for (int k = 0; k < K; k++) acc = fmaf(Hl[r][k], Wl[k * C + c], acc);
      out[row * C + c] = acc;
    }
  }
}

// ---------------- aggregation: one LW-lane sub-wave per node, lane = feature ----------------
// Edge loop is unrolled (16/4/1) with vectorized int4/float4 index loads to get
// many independent row-gathers in flight (latency-bound otherwise).

template <int C, int LW>
__global__ void aggregate(const float* __restrict__ m, const int* __restrict__ rowptr,
                          const int* __restrict__ csr_src, const float* __restrict__ csr_norm,
                          const float* __restrict__ dinv, const float* __restrict__ bias,
                          float* __restrict__ out, int n) {
  constexpr int NPB = 256 / LW;
  int sub = threadIdx.x / LW;
  int lane = threadIdx.x % LW;
  int cl = (lane < C) ? lane : lane - C;  // duplicate channel for LW>C lanes (branchless, in-bounds)
  int d = blockIdx.x * NPB + sub;
  if (d >= n) return;
  int start = rowptr[d], end = rowptr[d + 1];
  float dd = dinv[d];
  float acc = dd * dd * m[(size_t)d * C + cl];  // self loop
  int j = start;
  // prologue to 4-alignment (csr base is 256B aligned)
  int aligned = (start + 3) & ~3;
  int pre_end = aligned < end ? aligned : end;
  for (; j < pre_end; j++) acc += csr_norm[j] * m[(size_t)csr_src[j] * C + cl];
  // 16-wide: 16 independent gathers in flight
  for (; j + 16 <= end; j += 16) {
    int4 s0 = *(const int4*)(csr_src + j);
    int4 s1 = *(const int4*)(csr_src + j + 4);
    int4 s2 = *(const int4*)(csr_src + j + 8);
    int4 s3 = *(const int4*)(csr_src + j + 12);
    float4 w0 = *(const float4*)(csr_norm + j);
    float4 w1 = *(const float4*)(csr_norm + j + 4);
    float4 w2 = *(const float4*)(csr_norm + j + 8);
    float4 w3 = *(const float4*)(csr_norm + j + 12);
    float v0 = m[(size_t)s0.x * C + cl], v1 = m[(size_t)s0.y * C + cl];
    float v2 = m[(size_t)s0.z * C + cl], v3 = m[(size_t)s0.w * C + cl];
    float v4 = m[(size_t)s1.x * C + cl], v5 = m[(size_t)s1.y * C + cl];
    float v6 = m[(size_t)s1.z * C + cl], v7 = m[(size_t)s1.w * C + cl];
    float v8 = m[(size_t)s2.x * C + cl], v9 = m[(size_t)s2.y * C + cl];
    float va = m[(size_t)s2.z * C + cl], vb = m[(size_t)s2.w * C + cl];
    float vc = m[(size_t)s3.x * C + cl], vd = m[(size_t)s3.y * C + cl];
    float ve = m[(size_t)s3.z * C + cl], vf = m[(size_t)s3.w * C + cl];
    acc += w0.x * v0 + w0.y * v1 + w0.z * v2 + w0.w * v3;
    acc += w1.x * v4 + w1.y * v5 + w1.z * v6 + w1.w * v7;
    acc += w2.x * v8 + w2.y * v9 + w2.z * va + w2.w * vb;
    acc += w3.x * vc + w3.y * vd + w3.z * ve + w3.w * vf;
  }
  // 4-wide
  for (; j + 4 <= end; j += 4) {
    int4 s0 = *(const int4*)(csr_src + j);
    float4 w0 = *(const float4*)(csr_norm + j);
    float v0 = m[(size_t)s0.x * C + cl], v1 = m[(size_t)s0.y * C + cl];
    float v2 = m[(size_t)s0.z * C + cl], v3 = m[(size_t)s0.w * C + cl];
    acc += w0.x * v0 + w0.y * v1 + w0.z * v2 + w0.w * v3;
  }
  for (; j < end; j++) acc += csr_norm[j] * m[(size_t)csr_src[j] * C + cl];
  if (lane < C) out[(size_t)d * C + lane] = acc + bias[lane];
}

// ---------------- BN stats / finalize / apply ----------------

template <int C>
__global__ void bn_stats(const float* __restrict__ h, float* __restrict__ gsum,
                         float* __restrict__ gsq, int n) {
  __shared__ float ssum[256], ssq[256];
  const int Y = 256 / C;
  int tid = threadIdx.x;
  int c = tid % C, y = tid / C;
  float s = 0.f, q = 0.f;
  if (tid < C * Y) {
    for (int r = blockIdx.x * Y + y; r < n; r += gridDim.x * Y) {
      float v = h[r * C + c];
      s += v;
      q += v * v;
    }
  }
  ssum[tid] = s;
  ssq[tid] = q;
  __syncthreads();
  if (tid < C) {
    for (int yy = 1; yy < Y; yy++) {
      s += ssum[tid + yy * C];
      q += ssq[tid + yy * C];
    }
    atomicAdd(&gsum[tid], s);
    atomicAdd(&gsq[tid], q);
  }
}

__global__ void bn_finalize(const float* __restrict__ gsum, const float* __restrict__ gsq,
                            const float* __restrict__ g, const float* __restrict__ beta,
                            float* __restrict__ scale, float* __restrict__ shift, int C,
                            float invn) {
  int i = threadIdx.x;
  if (i < C) {
    float mean = gsum[i] * invn;
    float var = gsq[i] * invn - mean * mean;
    var = fmaxf(var, 0.f);
    float inv = rsqrtf(var + BN_EPS_F);
    float sc = g[i] * inv;
    scale[i] = sc;
    shift[i] = beta[i] - mean * sc;
  }
}

__global__ void bn_apply_out(const float* __restrict__ h, const float* __restrict__ scale,
                             const float* __restrict__ shift, float* __restrict__ out, int total) {
  int i = blockIdx.x * blockDim.x + threadIdx.x;
  if (i < total) {
    int c = i & 31;
    out[i] = h[i] * scale[c] + shift[c];
  }
}

// ---------------- launch ----------------

extern "C" void kernel_launch(void* const* d_in, const int* in_sizes, int n_in,
                              void* d_out, int out_size, void* d_ws, size_t ws_size,
                              hipStream_t stream) {
  const float* x = (const float*)d_in[0];
  const int* ei = (const int*)d_in[1];
  const float* W1 = (const float*)d_in[2];
  const float* b1 = (const float*)d_in[3];
  const float* g1 = (const float*)d_in[4];
  const float* be1 = (const float*)d_in[5];
  const float* W2 = (const float*)d_in[6];
  const float* b2 = (const float*)d_in[7];
  const float* g2 = (const float*)d_in[8];
  const float* be2 = (const float*)d_in[9];
  const float* W3 = (const float*)d_in[10];
  const float* b3 = (const float*)d_in[11];
  const float* g3 = (const float*)d_in[12];
  const float* be3 = (const float*)d_in[13];
  float* out = (float*)d_out;

  const int* src = ei;
  const int* dst = ei + NE;

  char* ws = (char*)d_ws;
  size_t off = 0;
  auto alloc = [&](size_t bytes) -> void* {
    void* p = ws + off;
    off += bytes;
    off = (off + 255) & ~(size_t)255;
    return p;
  };
  int* deg = (int*)alloc(NN * 4);
  int* rowptr = (int*)alloc((NN + 1) * 4);
  int* cursor = (int*)alloc(NN * 4);
  int* bsums = (int*)alloc(128 * 4);
  int* csr_src = (int*)alloc(NE * 4);
  float* csr_norm = (float*)alloc(NE * 4);
  float* dinv = (float*)alloc(NN * 4);
  float* gsum = (float*)alloc(3 * 128 * 4);
  float* scsh = (float*)alloc(3 * 128 * 4);
  float* bufA = (float*)alloc((size_t)NN * 64 * 4);
  float* bufB = (float*)alloc((size_t)NN * 64 * 4);

  hipMemsetAsync(deg, 0, NN * 4, stream);
  hipMemsetAsync(gsum, 0, 3 * 128 * 4, stream);

  const int nb = (NN + 1023) / 1024;  // 98
  count_deg<<<(NE + 255) / 256, 256, 0, stream>>>(dst, deg, NE);
  scan_block_sums<<<nb, 256, 0, stream>>>(deg, bsums, NN);
  scan_bsums<<<1, 128, 0, stream>>>(bsums, nb, rowptr, NN);
  scan_write_rowptr<<<nb, 256, 0, stream>>>(deg, bsums, rowptr, cursor, NN);
  compute_dinv<<<(NN + 255) / 256, 256, 0, stream>>>(deg, dinv, NN);
  fill_csr<<<(NE + 255) / 256, 256, 0, stream>>>(src, dst, dinv, cursor, csr_src, csr_norm, NE);

  const float invn = 1.f / (float)NN;

  // layer 1: x[.,20] @ W1 -> 64
  gemm_affine<20, 64, 4><<<(NN + 3) / 4, 256, 0, stream>>>(x, W1, nullptr, nullptr, bufA, NN);
  aggregate<64, 64><<<(NN + 3) / 4, 256, 0, stream>>>(bufA, rowptr, csr_src, csr_norm, dinv, b1, bufB, NN);
  bn_stats<64><<<256, 256, 0, stream>>>(bufB, gsum + 0, gsum + 64, NN);
  bn_finalize<<<1, 64, 0, stream>>>(gsum + 0, gsum + 64, g1, be1, scsh + 0, scsh + 64, 64, invn);

  // layer 2: relu(bn(h)) @ W2 -> 48
  gemm_affine<64, 48, 5><<<(NN + 4) / 5, 256, 0, stream>>>(bufB, W2, scsh + 0, scsh + 64, bufA, NN);
  aggregate<48, 64><<<(NN + 3) / 4, 256, 0, stream>>>(bufA, rowptr, csr_src, csr_norm, dinv, b2, bufB, NN);
  bn_stats<48><<<256, 256, 0, stream>>>(bufB, gsum + 128, gsum + 192, NN);
  bn_finalize<<<1, 64, 0, stream>>>(gsum + 128, gsum + 192, g2, be2, scsh + 128, scsh + 192, 48, invn);

  // layer 3: relu(bn(h)) @ W3 -> 32
  gemm_affine<48, 32, 8><<<(NN + 7) / 8, 256, 0, stream>>>(bufB, W3, scsh + 128, scsh + 192, bufA, NN);
  aggregate<32, 32><<<(NN + 7) / 8, 256, 0, stream>>>(bufA, rowptr, csr_src, csr_norm, dinv, b3, bufB, NN);
  bn_stats<32><<<256, 256, 0, stream>>>(bufB, gsum + 256, gsum + 320, NN);
  bn_finalize<<<1, 64, 0, stream>>>(gsum + 256, gsum + 320, g3, be3, scsh + 256, scsh + 320, 32, invn);

  bn_apply_out<<<(NN * 32 + 255) / 256, 256, 0, stream>>>(bufB, scsh + 256, scsh + 320, out, NN * 32);
}